// Round 4
// baseline (322.303 us; speedup 1.0000x reference)
//
#include <hip/hip_runtime.h>

// GuidedMoEBasic single-launch: B=16, D=64, H=768, NE=7, FEAT=776.
// Affine collapse: o[e,n,:] = flat[n]@(W1[e]@W2[e]) + (b1[e]@W2[e]+b2[e]),
// flat[n]=[conc[b,t],conc[b,end]] -> per-row 12-float pc vectors; pairs O(1).
// Grid: 1024 row-blocks (emotion) + 194 M-blocks (W1@W2, 1 row/wave) +
// 1 bias/gate block + 16 batch blocks (MFMA proj + pairs), sharded
// arrive/depart counters (replay-safe: reset in-kernel, immune to ws poison).

#define NE_    7
#define H_     768
#define FEAT_  776
#define NROW   1024
#define PAIRS  2080
#define KP     800          // padded K (25 * 32)
#define BTJ    12

#define NBLK_ROW 1024
#define NBLK_M   194        // 194 * 16 waves = 3104 M-rows
#define BIAS_BLK 1218
#define BATCH0   1219
#define NPRODM   195        // M blocks + bias block
#define NBATCH   16
#define NBLKS    1235

__device__ int g_arrM = 0;
__device__ int g_arrRow[NBATCH] = {};
__device__ int g_depart = 0;

typedef float f32x4 __attribute__((ext_vector_type(4)));
typedef short bf16x8 __attribute__((ext_vector_type(8)));

__device__ __forceinline__ unsigned short f2b(float x) {
    unsigned u = __float_as_uint(x);
    u += 0x7FFFu + ((u >> 16) & 1u);
    return (unsigned short)(u >> 16);
}

__global__ __launch_bounds__(1024) void kOne(
        const float* __restrict__ pooled,
        const int*   __restrict__ spk,
        const float* __restrict__ emo_w,
        const float* __restrict__ emo_b,
        const float* __restrict__ gate_w,
        const float* __restrict__ gate_b,
        const float* __restrict__ w1,
        const float* __restrict__ b1,
        const float* __restrict__ w2,
        const float* __restrict__ b2,
        float* __restrict__ out,                // [1024*7] emo | [33280*2] cause
        unsigned short* __restrict__ wsBt,      // [12][800] bf16
        float* __restrict__ wsbc) {             // [4] f32
    const int blk = blockIdx.x;
    const int tid = threadIdx.x;
    const int l   = tid & 63;
    const int wv  = tid >> 6;

    __shared__ float part[4 * 64 * 16];         // 16 KB
    __shared__ float redE[16][NE_];

    // ================= emotion row blocks =================
    if (blk < NBLK_ROW) {
        const int row = blk;
        float acc[NE_] = {0.f, 0.f, 0.f, 0.f, 0.f, 0.f, 0.f};
        if (tid < H_) {
            const float p = pooled[(size_t)row * H_ + tid];
#pragma unroll
            for (int k = 0; k < NE_; k++) acc[k] = p * emo_w[tid * NE_ + k];
        }
#pragma unroll
        for (int off = 32; off; off >>= 1)
#pragma unroll
            for (int k = 0; k < NE_; k++) acc[k] += __shfl_down(acc[k], off);
        if (l == 0)
#pragma unroll
            for (int k = 0; k < NE_; k++) redE[wv][k] = acc[k];
        __syncthreads();
        if (tid < NE_) {
            float v = emo_b[tid];
#pragma unroll
            for (int w = 0; w < 16; w++) v += redE[w][tid];
            out[row * NE_ + tid] = v;
        }
        __threadfence();
        __syncthreads();
        if (tid == 0)
            __hip_atomic_fetch_add(&g_arrRow[row >> 6], 1, __ATOMIC_RELEASE,
                                   __HIP_MEMORY_SCOPE_AGENT);
        return;
    }

    // ================= M blocks: one M-row per wave =================
    if (blk < BIAS_BLK) {
        const int mr = (blk - NBLK_ROW) * 16 + wv;        // 0..3103
        const int e = mr / 1552, rr = mr - e * 1552;
        const float4 a = ((const float4*)(w1 + ((size_t)e * 1552 + rr) * 256))[l];
        const float4* wvp = (const float4*)(w2 + (size_t)e * 512);
        const float4 q0 = wvp[l * 2], q1 = wvp[l * 2 + 1];
        float a0 = a.x * q0.x + a.y * q0.z + a.z * q1.x + a.w * q1.z;
        float a1 = a.x * q0.y + a.y * q0.w + a.z * q1.y + a.w * q1.w;
#pragma unroll
        for (int off = 32; off; off >>= 1) {
            a0 += __shfl_down(a0, off);
            a1 += __shfl_down(a1, off);
        }
        if (l == 0) {
            const int half = rr / FEAT_, f = rr - half * FEAT_;
            const int j = half * 4 + e * 2;
            wsBt[j * KP + f]       = f2b(a0);
            wsBt[(j + 1) * KP + f] = f2b(a1);
        }
        __threadfence();
        __syncthreads();
        if (tid == 0)
            __hip_atomic_fetch_add(&g_arrM, 1, __ATOMIC_RELEASE, __HIP_MEMORY_SCOPE_AGENT);
        return;
    }

    // ================= bias / gate / pad block =================
    if (blk == BIAS_BLK) {
        if (wv < 2) {
            const int e = wv;
            const float4 a = ((const float4*)(b1 + e * 256))[l];
            const float4* wvp = (const float4*)(w2 + (size_t)e * 512);
            const float4 q0 = wvp[l * 2], q1 = wvp[l * 2 + 1];
            float a0 = a.x * q0.x + a.y * q0.z + a.z * q1.x + a.w * q1.z;
            float a1 = a.x * q0.y + a.y * q0.w + a.z * q1.y + a.w * q1.w;
#pragma unroll
            for (int off = 32; off; off >>= 1) {
                a0 += __shfl_down(a0, off);
                a1 += __shfl_down(a1, off);
            }
            if (l == 0) {
                wsbc[e * 2]     = a0 + b2[e * 2];
                wsbc[e * 2 + 1] = a1 + b2[e * 2 + 1];
            }
        }
        for (int gi = tid; gi < 3104; gi += 1024) {
            const int half = gi / 1552, r2 = gi - half * 1552, f = r2 >> 1, c = r2 & 1;
            wsBt[(8 + half * 2 + c) * KP + f] =
                f2b(gate_w[((size_t)half * FEAT_ + f) * 2 + c]);
        }
        for (int z = tid; z < BTJ * 24; z += 1024) {
            const int j = z / 24, f = FEAT_ + z % 24;
            wsBt[j * KP + f] = 0;
        }
        __threadfence();
        __syncthreads();
        if (tid == 0)
            __hip_atomic_fetch_add(&g_arrM, 1, __ATOMIC_RELEASE, __HIP_MEMORY_SCOPE_AGENT);
        return;
    }

    // ================= batch blocks =================
    const int b = blk - BATCH0, R0 = b * 64;
    const int m = wv & 3, kq = wv >> 2, g = l >> 4, n = l & 15;
    const int arow = R0 + m * 16 + n;                  // A-fragment global row
    const int kt0 = (kq == 0) ? 0 : (1 + 6 * kq);      // k-steps: 7,6,6,6
    const int cnt = (kq == 0) ? 7 : 6;

    // pre-load A fragments (producer-independent; overlaps the spin)
    bf16x8 af[7];
#pragma unroll
    for (int s = 0; s < 7; ++s) {
        bf16x8 t = {0, 0, 0, 0, 0, 0, 0, 0};
        if (s < cnt) {
            const int k0 = (kt0 + s) * 32 + g * 8;
            if (k0 < H_) {
                const float4 u0 = *(const float4*)(pooled + (size_t)arow * H_ + k0);
                const float4 u1 = *(const float4*)(pooled + (size_t)arow * H_ + k0 + 4);
                t[0] = (short)f2b(u0.x); t[1] = (short)f2b(u0.y);
                t[2] = (short)f2b(u0.z); t[3] = (short)f2b(u0.w);
                t[4] = (short)f2b(u1.x); t[5] = (short)f2b(u1.y);
                t[6] = (short)f2b(u1.z); t[7] = (short)f2b(u1.w);
            }
        }
        af[s] = t;
    }

    // gate: wait for all producers this batch depends on
    if (tid == 0) {
        while (__hip_atomic_load(&g_arrM, __ATOMIC_ACQUIRE, __HIP_MEMORY_SCOPE_AGENT) < NPRODM ||
               __hip_atomic_load(&g_arrRow[b], __ATOMIC_ACQUIRE, __HIP_MEMORY_SCOPE_AGENT) < 64)
            __builtin_amdgcn_s_sleep(2);
    }
    __syncthreads();
    __threadfence();
    if (tid == 0) {
        __hip_atomic_store(&g_arrRow[b], 0, __ATOMIC_RELAXED, __HIP_MEMORY_SCOPE_AGENT);
        const int d = __hip_atomic_fetch_add(&g_depart, 1, __ATOMIC_ACQ_REL,
                                             __HIP_MEMORY_SCOPE_AGENT);
        if (d == NBATCH - 1) {
            __hip_atomic_store(&g_arrM, 0, __ATOMIC_RELAXED, __HIP_MEMORY_SCOPE_AGENT);
            __hip_atomic_store(&g_depart, 0, __ATOMIC_RELAXED, __HIP_MEMORY_SCOPE_AGENT);
        }
    }

    // fix the emotion/spk A-fragment (kt=24, g=0 -> k 768..775)
    if (kq == 3 && g == 0) {
        bf16x8 t;
        t[0] = (short)f2b(out[(size_t)arow * NE_ + 0]);
        t[1] = (short)f2b(out[(size_t)arow * NE_ + 1]);
        t[2] = (short)f2b(out[(size_t)arow * NE_ + 2]);
        t[3] = (short)f2b(out[(size_t)arow * NE_ + 3]);
        t[4] = (short)f2b(out[(size_t)arow * NE_ + 4]);
        t[5] = (short)f2b(out[(size_t)arow * NE_ + 5]);
        t[6] = (short)f2b(out[(size_t)arow * NE_ + 6]);
        t[7] = (short)f2b((float)spk[arow]);
        af[5] = t;
    }

    // MFMA: 25 k-steps split over 4 k-quarters; 4 m-tiles; N=16 (12 used)
    f32x4 acc = {0.f, 0.f, 0.f, 0.f};
#pragma unroll
    for (int s = 0; s < 7; ++s) {
        if (s < cnt) {
            const int k0 = (kt0 + s) * 32 + g * 8;
            bf16x8 bfr = {0, 0, 0, 0, 0, 0, 0, 0};
            if (n < BTJ && k0 < FEAT_)
                bfr = *(const bf16x8*)(wsBt + n * KP + k0);
            acc = __builtin_amdgcn_mfma_f32_16x16x32_bf16(af[s], bfr, acc, 0, 0, 0);
        }
    }
#pragma unroll
    for (int i = 0; i < 4; ++i)
        part[(kq * 64 + m * 16 + g * 4 + i) * 16 + n] = acc[i];
    __syncthreads();

    // cross-kq reduce into part[0]
    {
        const int r = tid >> 4, c = tid & 15;
        const float v = part[r * 16 + c] + part[(64 + r) * 16 + c] +
                        part[(128 + r) * 16 + c] + part[(192 + r) * 16 + c];
        part[r * 16 + c] = v;
    }
    __syncthreads();

    // pairs: O(1) each from part[0] (pc[64][16])
    const float bc0 = wsbc[0], bc1 = wsbc[1], bc2 = wsbc[2], bc3 = wsbc[3];
    const float gb0 = gate_b[0], gb1 = gate_b[1];
    float* oc = out + (size_t)NROW * NE_ + (size_t)b * PAIRS * 2;
    for (int p = tid; p < PAIRS; p += 1024) {
        int end = (int)((sqrtf(8.0f * (float)p + 1.0f) - 1.0f) * 0.5f);
        while ((end + 1) * (end + 2) / 2 <= p) end++;
        while (end * (end + 1) / 2 > p) end--;
        const int tt = p - end * (end + 1) / 2;
        const float* pt = part + tt * 16;
        const float* pe = part + end * 16;
        const float g0 = pt[8] + pe[10] + gb0;
        const float g1 = pt[9] + pe[11] + gb1;
        oc[p * 2]     = (pt[0] + pe[4] + bc0) * g0 + (pt[2] + pe[6] + bc2) * g1;
        oc[p * 2 + 1] = (pt[1] + pe[5] + bc1) * g0 + (pt[3] + pe[7] + bc3) * g1;
    }
}

// ---------------------------------------------------------------------------
extern "C" void kernel_launch(void* const* d_in, const int* in_sizes, int n_in,
                              void* d_out, int out_size, void* d_ws, size_t ws_size,
                              hipStream_t stream) {
    const float* pooled = (const float*)d_in[0];
    const int*   spk    = (const int*)d_in[1];
    const float* emo_w  = (const float*)d_in[2];
    const float* emo_b  = (const float*)d_in[3];
    const float* gate_w = (const float*)d_in[4];
    const float* gate_b = (const float*)d_in[5];
    const float* exp_w1 = (const float*)d_in[6];
    const float* exp_b1 = (const float*)d_in[7];
    const float* exp_w2 = (const float*)d_in[8];
    const float* exp_b2 = (const float*)d_in[9];

    float* out = (float*)d_out;
    unsigned short* wsBt = (unsigned short*)d_ws;            // 12*800*2 = 19200 B
    float* wsbc = (float*)((char*)d_ws + BTJ * KP * 2);      // 16 B

    hipLaunchKernelGGL(kOne, dim3(NBLKS), dim3(1024), 0, stream,
                       pooled, spk, emo_w, emo_b, gate_w, gate_b,
                       exp_w1, exp_b1, exp_w2, exp_b2, out, wsBt, wsbc);
}

// Round 5
// 19.992 us; speedup vs baseline: 16.1212x; 16.1212x over previous
//
#include <hip/hip_runtime.h>

// GuidedMoEBasic, 2 launches, zero in-kernel global sync.
// B=16, D=64, H=768, NE=7, FEAT=776. Affine collapse of the expert MLP:
//   o[e,n,:] = flat[n]@(W1[e]@W2[e]) + (b1[e]@W2[e]+b2[e]),
//   flat[n] = [conc[b,t], conc[b,end]]  ->  per-row 12-float pc vectors,
//   pairs are O(1) from pc. Bt[12][800] bf16 = 8 M-columns + 4 gate columns.
// K1: emotion rows + M rows + misc (no deps). K2: MFMA projection + pairs.
// Kernel boundary = the global barrier (in-kernel fencing measured ~0.3us/block).

#define NE_    7
#define H_     768
#define FEAT_  776
#define NROW   1024
#define PAIRS  2080
#define KP     800          // padded K (25 * 32)
#define BTJ    12
#define NBATCH 16

typedef float f32x4 __attribute__((ext_vector_type(4)));
typedef short bf16x8 __attribute__((ext_vector_type(8)));

__device__ __forceinline__ unsigned short f2b(float x) {
    unsigned u = __float_as_uint(x);
    u += 0x7FFFu + ((u >> 16) & 1u);
    return (unsigned short)(u >> 16);
}

// ===========================================================================
// K1: blocks 0..63 emotion (1 row/wave), 64..257 M (1 M-row/wave), 258 misc.
// ===========================================================================
__global__ __launch_bounds__(1024) void kPrep(
        const float* __restrict__ pooled,
        const float* __restrict__ emo_w,
        const float* __restrict__ emo_b,
        const float* __restrict__ gate_w,
        const float* __restrict__ w1,
        const float* __restrict__ b1,
        const float* __restrict__ w2,
        const float* __restrict__ b2,
        float* __restrict__ out,                // emotion region [1024*7]
        unsigned short* __restrict__ wsBt,      // [12][800] bf16
        float* __restrict__ wsbc) {             // [4] f32
    const int blk = blockIdx.x;
    const int tid = threadIdx.x;
    const int l   = tid & 63;
    const int wv  = tid >> 6;

    if (blk < 64) {
        // ---------------- emotion: one row per wave ----------------
        const int row = blk * 16 + wv;
        const float* pr = pooled + (size_t)row * H_;
        float acc[NE_] = {0.f, 0.f, 0.f, 0.f, 0.f, 0.f, 0.f};
#pragma unroll
        for (int i = 0; i < 12; ++i) {
            const float p = pr[l + 64 * i];
            const float* ew = emo_w + (size_t)(l + 64 * i) * NE_;
#pragma unroll
            for (int k = 0; k < NE_; ++k) acc[k] += p * ew[k];
        }
#pragma unroll
        for (int off = 32; off; off >>= 1)
#pragma unroll
            for (int k = 0; k < NE_; ++k) acc[k] += __shfl_down(acc[k], off);
        if (l == 0) {
#pragma unroll
            for (int k = 0; k < NE_; ++k)
                out[(size_t)row * NE_ + k] = acc[k] + emo_b[k];
        }
        return;
    }

    if (blk < 258) {
        // ---------------- M: one M-row per wave ----------------
        const int mr = (blk - 64) * 16 + wv;              // 0..3103
        const int e = mr / 1552, rr = mr - e * 1552;
        const float4 a = ((const float4*)(w1 + ((size_t)e * 1552 + rr) * 256))[l];
        const float4* wvp = (const float4*)(w2 + (size_t)e * 512);
        const float4 q0 = wvp[l * 2], q1 = wvp[l * 2 + 1];
        float a0 = a.x * q0.x + a.y * q0.z + a.z * q1.x + a.w * q1.z;
        float a1 = a.x * q0.y + a.y * q0.w + a.z * q1.y + a.w * q1.w;
#pragma unroll
        for (int off = 32; off; off >>= 1) {
            a0 += __shfl_down(a0, off);
            a1 += __shfl_down(a1, off);
        }
        if (l == 0) {
            const int half = rr / FEAT_, f = rr - half * FEAT_;
            const int j = half * 4 + e * 2;
            wsBt[j * KP + f]       = f2b(a0);
            wsBt[(j + 1) * KP + f] = f2b(a1);
        }
        return;
    }

    // ---------------- misc: bias consts, gate columns, zero pads ----------
    if (wv < 2) {
        const int e = wv;
        const float4 a = ((const float4*)(b1 + e * 256))[l];
        const float4* wvp = (const float4*)(w2 + (size_t)e * 512);
        const float4 q0 = wvp[l * 2], q1 = wvp[l * 2 + 1];
        float a0 = a.x * q0.x + a.y * q0.z + a.z * q1.x + a.w * q1.z;
        float a1 = a.x * q0.y + a.y * q0.w + a.z * q1.y + a.w * q1.w;
#pragma unroll
        for (int off = 32; off; off >>= 1) {
            a0 += __shfl_down(a0, off);
            a1 += __shfl_down(a1, off);
        }
        if (l == 0) {
            wsbc[e * 2]     = a0 + b2[e * 2];
            wsbc[e * 2 + 1] = a1 + b2[e * 2 + 1];
        }
    }
    for (int gi = tid; gi < 3104; gi += 1024) {
        const int half = gi / 1552, r2 = gi - half * 1552, f = r2 >> 1, c = r2 & 1;
        wsBt[(8 + half * 2 + c) * KP + f] =
            f2b(gate_w[((size_t)half * FEAT_ + f) * 2 + c]);
    }
    for (int z = tid; z < BTJ * 24; z += 1024) {
        const int j = z / 24, f = FEAT_ + z % 24;
        wsBt[j * KP + f] = 0;
    }
}

// ===========================================================================
// K2: 16 blocks (one per batch), 1024 threads: MFMA projection + O(1) pairs.
// ===========================================================================
__global__ __launch_bounds__(1024) void kProj(
        const float* __restrict__ pooled,
        const int*   __restrict__ spk,
        const float* __restrict__ gate_b,
        const unsigned short* __restrict__ wsBt,
        const float* __restrict__ wsbc,
        float* __restrict__ out) {              // emo (read) | cause (write)
    const int b   = blockIdx.x;
    const int tid = threadIdx.x;
    const int l   = tid & 63;
    const int wv  = tid >> 6;

    __shared__ float part[4 * 64 * 16];         // 16 KB

    const int R0 = b * 64;
    const int m = wv & 3, kq = wv >> 2, g = l >> 4, n = l & 15;
    const int arow = R0 + m * 16 + n;                  // A-fragment global row
    const int kt0 = (kq == 0) ? 0 : (1 + 6 * kq);      // k-steps: 7,6,6,6
    const int cnt = (kq == 0) ? 7 : 6;

    // A fragments from pooled (bf16-converted); kt=24,g=0 fixed up below.
    bf16x8 af[7];
#pragma unroll
    for (int s = 0; s < 7; ++s) {
        bf16x8 t = {0, 0, 0, 0, 0, 0, 0, 0};
        if (s < cnt) {
            const int k0 = (kt0 + s) * 32 + g * 8;
            if (k0 < H_) {
                const float4 u0 = *(const float4*)(pooled + (size_t)arow * H_ + k0);
                const float4 u1 = *(const float4*)(pooled + (size_t)arow * H_ + k0 + 4);
                t[0] = (short)f2b(u0.x); t[1] = (short)f2b(u0.y);
                t[2] = (short)f2b(u0.z); t[3] = (short)f2b(u0.w);
                t[4] = (short)f2b(u1.x); t[5] = (short)f2b(u1.y);
                t[6] = (short)f2b(u1.z); t[7] = (short)f2b(u1.w);
            }
        }
        af[s] = t;
    }
    // emotion/spk fragment (k 768..775): kq=3, s=5 -> kt=24, g=0
    if (kq == 3 && g == 0) {
        bf16x8 t;
        t[0] = (short)f2b(out[(size_t)arow * NE_ + 0]);
        t[1] = (short)f2b(out[(size_t)arow * NE_ + 1]);
        t[2] = (short)f2b(out[(size_t)arow * NE_ + 2]);
        t[3] = (short)f2b(out[(size_t)arow * NE_ + 3]);
        t[4] = (short)f2b(out[(size_t)arow * NE_ + 4]);
        t[5] = (short)f2b(out[(size_t)arow * NE_ + 5]);
        t[6] = (short)f2b(out[(size_t)arow * NE_ + 6]);
        t[7] = (short)f2b((float)spk[arow]);
        af[5] = t;
    }

    // 25 k-steps split over 4 k-quarters; 4 m-tiles; N=16 (12 used)
    f32x4 acc = {0.f, 0.f, 0.f, 0.f};
#pragma unroll
    for (int s = 0; s < 7; ++s) {
        if (s < cnt) {
            const int k0 = (kt0 + s) * 32 + g * 8;
            bf16x8 bfr = {0, 0, 0, 0, 0, 0, 0, 0};
            if (n < BTJ)
                bfr = *(const bf16x8*)(wsBt + n * KP + k0);
            acc = __builtin_amdgcn_mfma_f32_16x16x32_bf16(af[s], bfr, acc, 0, 0, 0);
        }
    }
#pragma unroll
    for (int i = 0; i < 4; ++i)
        part[(kq * 64 + m * 16 + g * 4 + i) * 16 + n] = acc[i];
    __syncthreads();

    // cross-kq reduce into part[0]
    {
        const int r = tid >> 4, c = tid & 15;
        const float v = part[r * 16 + c] + part[(64 + r) * 16 + c] +
                        part[(128 + r) * 16 + c] + part[(192 + r) * 16 + c];
        part[r * 16 + c] = v;
    }
    __syncthreads();

    // pairs: O(1) each from part[0] (pc[64][16])
    const float bc0 = wsbc[0], bc1 = wsbc[1], bc2 = wsbc[2], bc3 = wsbc[3];
    const float gb0 = gate_b[0], gb1 = gate_b[1];
    float* oc = out + (size_t)NROW * NE_ + (size_t)b * PAIRS * 2;
    for (int p = tid; p < PAIRS; p += 1024) {
        int end = (int)((sqrtf(8.0f * (float)p + 1.0f) - 1.0f) * 0.5f);
        while ((end + 1) * (end + 2) / 2 <= p) end++;
        while (end * (end + 1) / 2 > p) end--;
        const int tt = p - end * (end + 1) / 2;
        const float* pt = part + tt * 16;
        const float* pe = part + end * 16;
        const float g0 = pt[8] + pe[10] + gb0;
        const float g1 = pt[9] + pe[11] + gb1;
        oc[p * 2]     = (pt[0] + pe[4] + bc0) * g0 + (pt[2] + pe[6] + bc2) * g1;
        oc[p * 2 + 1] = (pt[1] + pe[5] + bc1) * g0 + (pt[3] + pe[7] + bc3) * g1;
    }
}

// ---------------------------------------------------------------------------
extern "C" void kernel_launch(void* const* d_in, const int* in_sizes, int n_in,
                              void* d_out, int out_size, void* d_ws, size_t ws_size,
                              hipStream_t stream) {
    const float* pooled = (const float*)d_in[0];
    const int*   spk    = (const int*)d_in[1];
    const float* emo_w  = (const float*)d_in[2];
    const float* emo_b  = (const float*)d_in[3];
    const float* gate_w = (const float*)d_in[4];
    const float* gate_b = (const float*)d_in[5];
    const float* exp_w1 = (const float*)d_in[6];
    const float* exp_b1 = (const float*)d_in[7];
    const float* exp_w2 = (const float*)d_in[8];
    const float* exp_b2 = (const float*)d_in[9];

    float* out = (float*)d_out;
    unsigned short* wsBt = (unsigned short*)d_ws;            // 12*800*2 = 19200 B
    float* wsbc = (float*)((char*)d_ws + BTJ * KP * 2);      // 16 B

    hipLaunchKernelGGL(kPrep, dim3(259), dim3(1024), 0, stream,
                       pooled, emo_w, emo_b, gate_w,
                       exp_w1, exp_b1, exp_w2, exp_b2, out, wsBt, wsbc);
    hipLaunchKernelGGL(kProj, dim3(NBATCH), dim3(1024), 0, stream,
                       pooled, spk, gate_b, wsBt, wsbc, out);
}